// Round 11
// baseline (245.045 us; speedup 1.0000x reference)
//
#include <hip/hip_runtime.h>

// SolventAccessibility — R11: consolidated counting-sort, zero global fp atomics.
// R10 evidence: harness floor ~105-110us (256MB ws poison fill = 41.7us/iter +
// input restore + graph nodes); our kernels ~60us across 6 launches, with
// scatter suffering ~8x write amplification (individual 8B stores).
// R11: 4 kernels. (1) pack+hist (4096-atom blocks); (2) prefix over block
// counts + ticket zero; (3) scatter with LDS bucket-grouping -> coalesced run
// writes, bucketBase derived in-block from totals; (4) accum with fused
// last-block finalize (threadfence+ticket).

#define PADV   (-999)
#define BATCH  8
#define NCHAIN 2
#define SEQL   1024
#define NALT   3
#define NRES   20
#define NATOMS 2000000
#define GLY    7
#define NRESID (BATCH * NCHAIN * SEQL)       // 16384 residues
#define NBINS  (NRESID * NALT)               // 49152 bins per output tensor
#define APB    4096                          // atoms per block (pack/scatter)
#define NBLK   ((NATOMS + APB - 1) / APB)    // 489
#define NBUCK  256                           // residue buckets (64 res each)
#define ACC_SUB 8                            // sub-blocks per bucket in accum

// pack word: r[13:0] | resname[18:14] | bb[19] | altmask[22:20]
#define PK_R(w)    ((int)((w) & 16383u))
#define PK_RES(w)  (((w) >> 14) & 31u)
#define PK_BB(w)   (((w) >> 19) & 1u)
#define PK_AM(w)   ((w) >> 20)

// workspace layout (bytes; all offsets 16B-aligned)
#define OFF_PACK  ((size_t)0)
#define SZ_PACK   ((size_t)NATOMS * 4)                    //  8,000,000
#define OFF_HIST  (OFF_PACK + SZ_PACK)
#define SZ_HIST   ((size_t)NBUCK * NBLK * 4)              //    500,736
#define OFF_TOT   (OFF_HIST + SZ_HIST)
#define SZ_TOT    ((size_t)1024)
#define OFF_TKT   (OFF_TOT + SZ_TOT)
#define SZ_TKT    ((size_t)1024)
#define OFF_SORT  (OFF_TKT + SZ_TKT)
#define SZ_SORT   ((size_t)NATOMS * 8)                    // 16,000,000
#define OFF_ACC   (OFF_SORT + SZ_SORT)
#define SZ_ACC    ((size_t)NBUCK * ACC_SUB * 384 * 4)     //  3,145,728
#define OFF_RES   (OFF_ACC + SZ_ACC)
#define SZ_RES    ((size_t)NBUCK * ACC_SUB * 64 * 4)      //    524,288
#define WS_NEED   (OFF_RES + SZ_RES)                      // ~28.2 MB

// ---------------------------------------------------------------------------
// Phase 1: pack 16 atoms/thread (4 groups of 4) + per-block bucket histogram.
// alternatives layout detection per-wave: int32 0/1 LE has byte==0 at offsets
// !=0 (mod 4); np.bool_ is ~70% nonzero there (P(all 64 zero) ~ 0.3^64).
// ---------------------------------------------------------------------------
__global__ __launch_bounds__(256)
void k_pack_hist(const int* __restrict__ desc,            // [NATOMS][5]
                 const unsigned char* __restrict__ altB,
                 const int* __restrict__ altI,
                 unsigned* __restrict__ pack,
                 unsigned* __restrict__ hist) {           // [NBUCK][NBLK]
    __shared__ unsigned h[NBUCK];
    h[threadIdx.x] = 0u;
    __syncthreads();

    const unsigned char probe = altB[(threadIdx.x & 63) * 4 + 1];
    const bool byteLayout = (__ballot(probe != 0) != 0ULL);

    const int blockBase = blockIdx.x * APB;
    #pragma unroll
    for (int g = 0; g < 4; ++g) {
        const int a0 = blockBase + (g * 256 + (int)threadIdx.x) * 4;
        if (a0 >= NATOMS) continue;        // NATOMS%4==0 -> full quad valid

        const int4* d4 = (const int4*)(desc + (size_t)a0 * 5);
        int4 q0 = d4[0], q1 = d4[1], q2 = d4[2], q3 = d4[3], q4 = d4[4];
        int an[4], rn[4], ch[4], bi[4], rs[4];
        an[0]=q0.x; rn[0]=q0.y; ch[0]=q0.z; bi[0]=q0.w; rs[0]=q1.x;
        an[1]=q1.y; rn[1]=q1.z; ch[1]=q1.w; bi[1]=q2.x; rs[1]=q2.y;
        an[2]=q2.z; rn[2]=q2.w; ch[2]=q3.x; bi[2]=q3.y; rs[2]=q3.z;
        an[3]=q3.w; rn[3]=q4.x; ch[3]=q4.y; bi[3]=q4.z; rs[3]=q4.w;

        unsigned am[4];
        if (byteLayout) {
            const unsigned* b3 = (const unsigned*)(altB + (size_t)a0 * 3);
            unsigned w0 = b3[0], w1 = b3[1], w2 = b3[2];
            unsigned char f[12];
            f[0]=w0; f[1]=w0>>8; f[2]=w0>>16; f[3]=w0>>24;
            f[4]=w1; f[5]=w1>>8; f[6]=w1>>16; f[7]=w1>>24;
            f[8]=w2; f[9]=w2>>8; f[10]=w2>>16; f[11]=w2>>24;
            #pragma unroll
            for (int k = 0; k < 4; ++k)
                am[k] = (f[k*3+0]?1u:0u) | (f[k*3+1]?2u:0u) | (f[k*3+2]?4u:0u);
        } else {
            const int4* i4 = (const int4*)(altI + (size_t)a0 * 3);
            int4 w0 = i4[0], w1 = i4[1], w2 = i4[2];
            int f[12] = {w0.x,w0.y,w0.z,w0.w, w1.x,w1.y,w1.z,w1.w,
                         w2.x,w2.y,w2.z,w2.w};
            #pragma unroll
            for (int k = 0; k < 4; ++k)
                am[k] = (f[k*3+0]?1u:0u) | (f[k*3+1]?2u:0u) | (f[k*3+2]?4u:0u);
        }

        uint4 pw;
        unsigned* pwp = (unsigned*)&pw;
        #pragma unroll
        for (int k = 0; k < 4; ++k) {
            const bool valid = (an[k] != PADV);
            const bool bb    = ((unsigned)an[k] <= 3u);   // BACKBONE {0,1,2,3}
            const int  r     = (bi[k] * NCHAIN + ch[k]) * SEQL + rn[k];
            const bool rOK   = ((unsigned)r < (unsigned)NRESID);
            const unsigned a = (valid && rOK) ? am[k] : 0u;
            pwp[k] = (rOK ? (unsigned)r : 0u)
                   | ((unsigned)(rs[k] & 31) << 14)
                   | ((bb ? 1u : 0u) << 19) | (a << 20);
            if (a) atomicAdd(&h[(pwp[k] >> 6) & 255u], 1u);
        }
        *(uint4*)(pack + a0) = pw;
    }
    __syncthreads();
    hist[(size_t)threadIdx.x * NBLK + blockIdx.x] = h[threadIdx.x];
}

// ---------------------------------------------------------------------------
// Phase 2: per-bucket exclusive scan over NBLK block counts (in place);
// writes bucket totals; zeroes finalize tickets.
// ---------------------------------------------------------------------------
__global__ __launch_bounds__(256)
void k_prefix1(unsigned* __restrict__ hist,
               unsigned* __restrict__ totals,
               unsigned* __restrict__ ticket) {
    __shared__ unsigned cnt[512];
    __shared__ unsigned csum[256];
    unsigned* h = hist + (size_t)blockIdx.x * NBLK;
    const int t = threadIdx.x;

    cnt[t]       = (t < NBLK) ? h[t] : 0u;
    cnt[t + 256] = (t + 256 < NBLK) ? h[t + 256] : 0u;
    __syncthreads();

    unsigned s = cnt[2 * t] + cnt[2 * t + 1];
    csum[t] = s;
    __syncthreads();
    for (int off = 1; off < 256; off <<= 1) {
        unsigned x = (t >= off) ? csum[t - off] : 0u;
        __syncthreads();
        csum[t] += x;
        __syncthreads();
    }
    if (t == 0) { totals[blockIdx.x] = csum[255]; ticket[blockIdx.x] = 0u; }

    unsigned run = (t == 0) ? 0u : csum[t - 1];
    const unsigned c0 = cnt[2 * t];
    cnt[2 * t]     = run;
    cnt[2 * t + 1] = run + c0;
    __syncthreads();
    if (t < NBLK)       h[t]       = cnt[t];
    if (t + 256 < NBLK) h[t + 256] = cnt[t + 256];
}

// ---------------------------------------------------------------------------
// Phase 3: scatter with LDS bucket-grouping. Each block stages its ~APB
// survivors grouped by bucket in LDS, then writes bucket-runs (~16 x 8B)
// contiguously -> coalesced. bucketBase derived in-block from totals.
// ---------------------------------------------------------------------------
__global__ __launch_bounds__(256)
void k_scatter(const unsigned* __restrict__ pack,
               const unsigned* __restrict__ hist,
               const unsigned* __restrict__ totals,
               uint2* __restrict__ sorted) {
    __shared__ unsigned sc[256];
    __shared__ unsigned gBase[256];
    __shared__ unsigned lofs[256];
    __shared__ unsigned lcnt[256];
    __shared__ unsigned wBuf[APB];
    __shared__ unsigned idxBuf[APB];

    const int t   = threadIdx.x;
    const int blk = blockIdx.x;

    // bucketBase scan from totals + this block's hist offset
    const unsigned own = totals[t];
    sc[t] = own;
    __syncthreads();
    for (int off = 1; off < 256; off <<= 1) {
        unsigned x = (t >= off) ? sc[t - off] : 0u;
        __syncthreads();
        sc[t] += x;
        __syncthreads();
    }
    gBase[t] = (sc[t] - own) + hist[(size_t)t * NBLK + blk];
    lcnt[t] = 0u;
    __syncthreads();

    // pass 1: load pack words (kept in regs), count per-bucket
    const int blockBase = blk * APB;
    uint4 pw[4];
    #pragma unroll
    for (int g = 0; g < 4; ++g) {
        const int a0 = blockBase + (g * 256 + t) * 4;
        if (a0 < NATOMS) {
            pw[g] = *(const uint4*)(pack + a0);
            const unsigned* p = (const unsigned*)&pw[g];
            #pragma unroll
            for (int k = 0; k < 4; ++k)
                if (p[k] >> 20) atomicAdd(&lcnt[(p[k] >> 6) & 255u], 1u);
        } else {
            pw[g] = make_uint4(0u, 0u, 0u, 0u);
        }
    }
    __syncthreads();

    // local exclusive scan of lcnt -> lofs
    const unsigned lown = lcnt[t];
    sc[t] = lown;
    __syncthreads();
    for (int off = 1; off < 256; off <<= 1) {
        unsigned x = (t >= off) ? sc[t - off] : 0u;
        __syncthreads();
        sc[t] += x;
        __syncthreads();
    }
    lofs[t] = sc[t] - lown;
    lcnt[t] = 0u;
    __syncthreads();
    const unsigned total = sc[255];

    // pass 2: place survivors bucket-grouped in LDS
    #pragma unroll
    for (int g = 0; g < 4; ++g) {
        const int a0 = blockBase + (g * 256 + t) * 4;
        const unsigned* p = (const unsigned*)&pw[g];
        #pragma unroll
        for (int k = 0; k < 4; ++k) {
            const unsigned w = p[k];
            if (w >> 20) {
                const unsigned b    = (w >> 6) & 255u;
                const unsigned slot = atomicAdd(&lcnt[b], 1u);
                const unsigned pos  = lofs[b] + slot;
                wBuf[pos]   = w;
                idxBuf[pos] = (unsigned)(a0 + k);
            }
        }
    }
    __syncthreads();

    // write out: consecutive j -> same bucket run -> consecutive dest
    for (unsigned j = (unsigned)t; j < total; j += 256u) {
        const unsigned w = wBuf[j];
        const unsigned b = (w >> 6) & 255u;
        const unsigned dest = gBase[b] + (j - lofs[b]);
        sorted[dest] = make_uint2(w, idxBuf[j]);
    }
}

// ---------------------------------------------------------------------------
// Phase 4: accumulate + fused finalize. block = (bucket b, sub). Last sub
// (ticket) reduces the 8 partials, normalizes, clips, writes out.
// ---------------------------------------------------------------------------
__global__ __launch_bounds__(256)
void k_accum_fin(const uint2* __restrict__ sorted,
                 const float* __restrict__ contRat,
                 const unsigned* __restrict__ totals,
                 unsigned* __restrict__ ticket,
                 float* __restrict__ accPart,       // [NBUCK][ACC_SUB][6][64]
                 unsigned* __restrict__ resPart,    // [NBUCK][ACC_SUB][64]
                 float* __restrict__ out,
                 const float* __restrict__ mcmax,
                 const float* __restrict__ mcmin,
                 const float* __restrict__ scmax,
                 const float* __restrict__ scmin) {
    __shared__ float acc[6 * 64];
    __shared__ unsigned ror[64];
    __shared__ unsigned sc[256];
    __shared__ unsigned eb[257];
    __shared__ int lastFlag;

    const int b   = blockIdx.x >> 3;
    const int sub = blockIdx.x & 7;
    const int t   = threadIdx.x;

    // bucketBase from totals
    const unsigned own = totals[t];
    sc[t] = own;
    __syncthreads();
    for (int off = 1; off < 256; off <<= 1) {
        unsigned x = (t >= off) ? sc[t - off] : 0u;
        __syncthreads();
        sc[t] += x;
        __syncthreads();
    }
    eb[t] = sc[t] - own;
    if (t == 255) eb[256] = sc[255];
    for (int j = t; j < 384; j += 256) acc[j] = 0.0f;
    if (t < 64) ror[t] = 0u;
    __syncthreads();

    const unsigned s0 = eb[b], s1 = eb[b + 1];
    const unsigned len = s1 - s0;
    const unsigned lo = s0 + (unsigned)(((unsigned long long)len * sub) >> 3);
    const unsigned hi = s0 + (unsigned)(((unsigned long long)len * (sub + 1)) >> 3);

    for (unsigned i = lo + t; i < hi; i += 256u) {
        const uint2 e = sorted[i];
        const unsigned w = e.x;
        const int lr = (int)(w & 63u);
        const unsigned am = PK_AM(w);
        const float* cr = contRat + (size_t)e.y * 3;
        const int pb = PK_BB(w) ? 0 : 3;
        if (PK_BB(w)) atomicOr(&ror[lr], (am << 5) | PK_RES(w));
        if (am & 1) atomicAdd(&acc[(pb + 0) * 64 + lr], cr[0]);
        if (am & 2) atomicAdd(&acc[(pb + 1) * 64 + lr], cr[1]);
        if (am & 4) atomicAdd(&acc[(pb + 2) * 64 + lr], cr[2]);
    }
    __syncthreads();

    float* ap = accPart + ((size_t)b * ACC_SUB + sub) * 384;
    for (int j = t; j < 384; j += 256) ap[j] = acc[j];
    if (t < 64)
        resPart[((size_t)b * ACC_SUB + sub) * 64 + t] = ror[t];
    __syncthreads();

    // ticket: last sub-block for this bucket finalizes
    if (t == 0) {
        __threadfence();
        const unsigned old = __hip_atomic_fetch_add(
            &ticket[b], 1u, __ATOMIC_ACQ_REL, __HIP_MEMORY_SCOPE_AGENT);
        lastFlag = (old == ACC_SUB - 1);
    }
    __syncthreads();
    if (!lastFlag || t >= 192) return;

    const int lr2 = t / 3, alt = t - lr2 * 3;
    float m = 0.0f, v = 0.0f;
    unsigned rb = 0u;
    #pragma unroll
    for (int s2 = 0; s2 < ACC_SUB; ++s2) {
        const float* p2 = accPart + ((size_t)b * ACC_SUB + s2) * 384;
        m  += p2[alt * 64 + lr2];
        v  += p2[(3 + alt) * 64 + lr2];
        rb |= resPart[((size_t)b * ACC_SUB + s2) * 64 + lr2];
    }
    if ((rb >> (5 + alt)) & 1u) {
        int resn = (int)(rb & 31u);
        if (resn > NRES - 1) resn = NRES - 1;
        m = (m - mcmin[resn]) / (mcmax[resn] - mcmin[resn]);
        v = ((rb & 31u) == GLY) ? 0.0f
                                : (v - scmin[resn]) / (scmax[resn] - scmin[resn]);
    }
    out[b * 192 + t]         = fminf(fmaxf(m, 0.0f), 1.0f);
    out[NBINS + b * 192 + t] = fminf(fmaxf(v, 0.0f), 1.0f);
}

// ---------------------------------------------------------------------------
// Fallback (tiny ws): flat agent-scope atomics (proven R1).
// ---------------------------------------------------------------------------
__global__ void k_init_flat(float* __restrict__ out, int* __restrict__ seq,
                            int* __restrict__ flag,
                            const unsigned char* __restrict__ altBytes) {
    int i = blockIdx.x * blockDim.x + threadIdx.x;
    if (i < NBINS) { out[i] = 0.0f; out[NBINS + i] = 0.0f; seq[i] = PADV; }
    if (blockIdx.x == 0 && threadIdx.x < 64) {
        unsigned char b = altBytes[threadIdx.x * 4 + 1];
        unsigned long long m = __ballot(b != 0);
        if (threadIdx.x == 0) *flag = (m != 0ULL) ? 1 : 0;
    }
}

__global__ void k_scatter_flat(const float* __restrict__ contRat,
                               const int* __restrict__ desc,
                               const unsigned char* __restrict__ altB,
                               const int* __restrict__ altI,
                               const int* __restrict__ flag,
                               float* __restrict__ mcArr,
                               float* __restrict__ scArr,
                               int* __restrict__ seq) {
    int a = blockIdx.x * blockDim.x + threadIdx.x;
    if (a >= NATOMS) return;
    const int atname  = desc[a * 5 + 0];
    const int resnum  = desc[a * 5 + 1];
    const int chain   = desc[a * 5 + 2];
    const int batchI  = desc[a * 5 + 3];
    const int resname = desc[a * 5 + 4];
    const bool valid = (atname != PADV);
    const bool is_bb = (atname >= 0) && (atname <= 3);
    const int  base  = ((batchI * NCHAIN + chain) * SEQL + resnum) * NALT;
    const bool byteLayout = (*flag != 0);
    #pragma unroll
    for (int alt = 0; alt < NALT; ++alt) {
        bool altv;
        if (byteLayout) altv = (altB[a * NALT + alt] != 0);
        else            altv = (altI[a * NALT + alt] != 0);
        if (altv && valid) {
            const float c = contRat[a * NALT + alt];
            const int   f = base + alt;
            if (is_bb) { atomicAdd(&mcArr[f], c); seq[f] = resname; }
            else       { atomicAdd(&scArr[f], c); }
        }
    }
}

__global__ void k_final_flat(float* __restrict__ mc, float* __restrict__ sc2,
                             const int* __restrict__ seq,
                             const float* __restrict__ mcmax,
                             const float* __restrict__ mcmin,
                             const float* __restrict__ scmax,
                             const float* __restrict__ scmin) {
    int i = blockIdx.x * blockDim.x + threadIdx.x;
    if (i >= NBINS) return;
    const int s = seq[i];
    float m = mc[i], v = sc2[i];
    if (s != PADV) {
        int idx = s < 0 ? 0 : (s > NRES - 1 ? NRES - 1 : s);
        m = (m - mcmin[idx]) / (mcmax[idx] - mcmin[idx]);
        if (s != GLY) v = (v - scmin[idx]) / (scmax[idx] - scmin[idx]);
        else          v = 0.0f;
    }
    mc[i]  = fminf(fmaxf(m, 0.0f), 1.0f);
    sc2[i] = fminf(fmaxf(v, 0.0f), 1.0f);
}

// ---------------------------------------------------------------------------
extern "C" void kernel_launch(void* const* d_in, const int* in_sizes, int n_in,
                              void* d_out, int out_size, void* d_ws, size_t ws_size,
                              hipStream_t stream) {
    const float* contRat = (const float*)d_in[0];
    const float* mcmax   = (const float*)d_in[1];
    const float* mcmin   = (const float*)d_in[2];
    const float* scmax   = (const float*)d_in[3];
    const float* scmin   = (const float*)d_in[4];
    const int*   desc    = (const int*)d_in[5];
    const void*  alts    = d_in[6];

    float* out = (float*)d_out;

    if (ws_size >= WS_NEED) {
        unsigned* pack  = (unsigned*)((char*)d_ws + OFF_PACK);
        unsigned* hist  = (unsigned*)((char*)d_ws + OFF_HIST);
        unsigned* tot   = (unsigned*)((char*)d_ws + OFF_TOT);
        unsigned* tkt   = (unsigned*)((char*)d_ws + OFF_TKT);
        uint2*    sorted= (uint2*)   ((char*)d_ws + OFF_SORT);
        float*    accP  = (float*)   ((char*)d_ws + OFF_ACC);
        unsigned* resP  = (unsigned*)((char*)d_ws + OFF_RES);

        k_pack_hist<<<NBLK, 256, 0, stream>>>(
            desc, (const unsigned char*)alts, (const int*)alts, pack, hist);
        k_prefix1<<<NBUCK, 256, 0, stream>>>(hist, tot, tkt);
        k_scatter<<<NBLK, 256, 0, stream>>>(pack, hist, tot, sorted);
        k_accum_fin<<<NBUCK * ACC_SUB, 256, 0, stream>>>(
            sorted, contRat, tot, tkt, accP, resP,
            out, mcmax, mcmin, scmax, scmin);
    } else {
        // ws too small: flat agent-scope atomic path
        int* seq  = (int*)d_ws;
        int* flag = seq + NBINS;
        const int binBlocks = (NBINS + 255) / 256;
        k_init_flat<<<binBlocks, 256, 0, stream>>>(out, seq, flag,
                                                   (const unsigned char*)alts);
        k_scatter_flat<<<(NATOMS + 255) / 256, 256, 0, stream>>>(
            contRat, desc,
            (const unsigned char*)alts, (const int*)alts, flag,
            out, out + NBINS, seq);
        k_final_flat<<<binBlocks, 256, 0, stream>>>(
            out, out + NBINS, seq, mcmax, mcmin, scmax, scmin);
    }
}

// Round 12
// 161.543 us; speedup vs baseline: 1.5169x; 1.5169x over previous
//
#include <hip/hip_runtime.h>

// SolventAccessibility — R12: counting-sort pipeline, zero global fp atomics,
// NO inter-block fences. R11 evidence: fused finalize (threadfence + agent
// ticket per block) cost ~100us — device-scope fences flush/invalidate the
// non-coherent per-XCD L2s and destroy pipeline locality. Reverted to
// kernel-boundary sync (R10 structure); kept R11's wins: 4096-atom pack
// blocks + LDS bucket-grouped scatter (coalesced run writes).

#define PADV   (-999)
#define BATCH  8
#define NCHAIN 2
#define SEQL   1024
#define NALT   3
#define NRES   20
#define NATOMS 2000000
#define GLY    7
#define NRESID (BATCH * NCHAIN * SEQL)       // 16384 residues
#define NBINS  (NRESID * NALT)               // 49152 bins per output tensor
#define APB    4096                          // atoms per block (pack/scatter)
#define NBLK   ((NATOMS + APB - 1) / APB)    // 489
#define NBUCK  256                           // residue buckets (64 res each)
#define ACC_SUB 8                            // sub-blocks per bucket in accum

// pack word: r[13:0] | resname[18:14] | bb[19] | altmask[22:20]
#define PK_R(w)    ((int)((w) & 16383u))
#define PK_RES(w)  (((w) >> 14) & 31u)
#define PK_BB(w)   (((w) >> 19) & 1u)
#define PK_AM(w)   ((w) >> 20)

// workspace layout (bytes; all offsets 16B-aligned)
#define OFF_PACK  ((size_t)0)
#define SZ_PACK   ((size_t)NATOMS * 4)                    //  8,000,000
#define OFF_HIST  (OFF_PACK + SZ_PACK)
#define SZ_HIST   ((size_t)NBUCK * NBLK * 4)              //    500,736
#define OFF_TOT   (OFF_HIST + SZ_HIST)
#define SZ_TOT    ((size_t)1024)
#define OFF_BB    (OFF_TOT + SZ_TOT)
#define SZ_BB     ((size_t)1280)                          // 257 u32, padded
#define OFF_SORT  (OFF_BB + SZ_BB)
#define SZ_SORT   ((size_t)NATOMS * 8)                    // 16,000,000
#define OFF_ACC   (OFF_SORT + SZ_SORT)
#define SZ_ACC    ((size_t)NBUCK * ACC_SUB * 384 * 4)     //  3,145,728
#define OFF_RES   (OFF_ACC + SZ_ACC)
#define SZ_RES    ((size_t)NBUCK * ACC_SUB * 64 * 4)      //    524,288
#define WS_NEED   (OFF_RES + SZ_RES)                      // ~28.2 MB

// ---------------------------------------------------------------------------
// Phase 1: pack 16 atoms/thread (4 quads) + per-block bucket histogram.
// alternatives layout detection per-wave: int32 0/1 LE has byte==0 at offsets
// !=0 (mod 4); np.bool_ is ~70% nonzero there (P(all 64 zero) ~ 0.3^64).
// ---------------------------------------------------------------------------
__global__ __launch_bounds__(256)
void k_pack_hist(const int* __restrict__ desc,            // [NATOMS][5]
                 const unsigned char* __restrict__ altB,
                 const int* __restrict__ altI,
                 unsigned* __restrict__ pack,
                 unsigned* __restrict__ hist) {           // [NBUCK][NBLK]
    __shared__ unsigned h[NBUCK];
    h[threadIdx.x] = 0u;
    __syncthreads();

    const unsigned char probe = altB[(threadIdx.x & 63) * 4 + 1];
    const bool byteLayout = (__ballot(probe != 0) != 0ULL);

    const int blockBase = blockIdx.x * APB;
    #pragma unroll
    for (int g = 0; g < 4; ++g) {
        const int a0 = blockBase + (g * 256 + (int)threadIdx.x) * 4;
        if (a0 >= NATOMS) continue;        // NATOMS%4==0 -> full quad valid

        const int4* d4 = (const int4*)(desc + (size_t)a0 * 5);
        int4 q0 = d4[0], q1 = d4[1], q2 = d4[2], q3 = d4[3], q4 = d4[4];
        int an[4], rn[4], ch[4], bi[4], rs[4];
        an[0]=q0.x; rn[0]=q0.y; ch[0]=q0.z; bi[0]=q0.w; rs[0]=q1.x;
        an[1]=q1.y; rn[1]=q1.z; ch[1]=q1.w; bi[1]=q2.x; rs[1]=q2.y;
        an[2]=q2.z; rn[2]=q2.w; ch[2]=q3.x; bi[2]=q3.y; rs[2]=q3.z;
        an[3]=q3.w; rn[3]=q4.x; ch[3]=q4.y; bi[3]=q4.z; rs[3]=q4.w;

        unsigned am[4];
        if (byteLayout) {
            const unsigned* b3 = (const unsigned*)(altB + (size_t)a0 * 3);
            unsigned w0 = b3[0], w1 = b3[1], w2 = b3[2];
            unsigned char f[12];
            f[0]=w0; f[1]=w0>>8; f[2]=w0>>16; f[3]=w0>>24;
            f[4]=w1; f[5]=w1>>8; f[6]=w1>>16; f[7]=w1>>24;
            f[8]=w2; f[9]=w2>>8; f[10]=w2>>16; f[11]=w2>>24;
            #pragma unroll
            for (int k = 0; k < 4; ++k)
                am[k] = (f[k*3+0]?1u:0u) | (f[k*3+1]?2u:0u) | (f[k*3+2]?4u:0u);
        } else {
            const int4* i4 = (const int4*)(altI + (size_t)a0 * 3);
            int4 w0 = i4[0], w1 = i4[1], w2 = i4[2];
            int f[12] = {w0.x,w0.y,w0.z,w0.w, w1.x,w1.y,w1.z,w1.w,
                         w2.x,w2.y,w2.z,w2.w};
            #pragma unroll
            for (int k = 0; k < 4; ++k)
                am[k] = (f[k*3+0]?1u:0u) | (f[k*3+1]?2u:0u) | (f[k*3+2]?4u:0u);
        }

        uint4 pw;
        unsigned* pwp = (unsigned*)&pw;
        #pragma unroll
        for (int k = 0; k < 4; ++k) {
            const bool valid = (an[k] != PADV);
            const bool bb    = ((unsigned)an[k] <= 3u);   // BACKBONE {0,1,2,3}
            const int  r     = (bi[k] * NCHAIN + ch[k]) * SEQL + rn[k];
            const bool rOK   = ((unsigned)r < (unsigned)NRESID);
            const unsigned a = (valid && rOK) ? am[k] : 0u;
            pwp[k] = (rOK ? (unsigned)r : 0u)
                   | ((unsigned)(rs[k] & 31) << 14)
                   | ((bb ? 1u : 0u) << 19) | (a << 20);
            if (a) atomicAdd(&h[(pwp[k] >> 6) & 255u], 1u);
        }
        *(uint4*)(pack + a0) = pw;
    }
    __syncthreads();
    hist[(size_t)threadIdx.x * NBLK + blockIdx.x] = h[threadIdx.x];
}

// ---------------------------------------------------------------------------
// Phase 2a: per-bucket exclusive scan over NBLK block counts (in place);
// writes bucket totals.
// ---------------------------------------------------------------------------
__global__ __launch_bounds__(256)
void k_prefix1(unsigned* __restrict__ hist, unsigned* __restrict__ totals) {
    __shared__ unsigned cnt[512];
    __shared__ unsigned csum[256];
    unsigned* h = hist + (size_t)blockIdx.x * NBLK;
    const int t = threadIdx.x;

    cnt[t]       = (t < NBLK) ? h[t] : 0u;
    cnt[t + 256] = (t + 256 < NBLK) ? h[t + 256] : 0u;
    __syncthreads();

    unsigned s = cnt[2 * t] + cnt[2 * t + 1];
    csum[t] = s;
    __syncthreads();
    for (int off = 1; off < 256; off <<= 1) {
        unsigned x = (t >= off) ? csum[t - off] : 0u;
        __syncthreads();
        csum[t] += x;
        __syncthreads();
    }
    if (t == 0) totals[blockIdx.x] = csum[255];

    unsigned run = (t == 0) ? 0u : csum[t - 1];
    const unsigned c0 = cnt[2 * t];
    cnt[2 * t]     = run;
    cnt[2 * t + 1] = run + c0;
    __syncthreads();
    if (t < NBLK)       h[t]       = cnt[t];
    if (t + 256 < NBLK) h[t + 256] = cnt[t + 256];
}

// ---------------------------------------------------------------------------
// Phase 2b: exclusive scan of bucket totals -> bucketBase[257].
// ---------------------------------------------------------------------------
__global__ __launch_bounds__(256)
void k_prefix2(const unsigned* __restrict__ totals,
               unsigned* __restrict__ bucketBase) {
    __shared__ unsigned s[256];
    const int t = threadIdx.x;
    const unsigned own = totals[t];
    s[t] = own;
    __syncthreads();
    for (int off = 1; off < 256; off <<= 1) {
        unsigned x = (t >= off) ? s[t - off] : 0u;
        __syncthreads();
        s[t] += x;
        __syncthreads();
    }
    bucketBase[t] = s[t] - own;
    if (t == 255) bucketBase[256] = s[255];
}

// ---------------------------------------------------------------------------
// Phase 3: scatter with LDS bucket-grouping. Each block stages its ~APB
// survivors grouped by bucket in LDS, then writes bucket-runs contiguously.
// ---------------------------------------------------------------------------
__global__ __launch_bounds__(256)
void k_scatter(const unsigned* __restrict__ pack,
               const unsigned* __restrict__ hist,
               const unsigned* __restrict__ bucketBase,
               uint2* __restrict__ sorted) {
    __shared__ unsigned sc[256];
    __shared__ unsigned gBase[256];
    __shared__ unsigned lofs[256];
    __shared__ unsigned lcnt[256];
    __shared__ unsigned wBuf[APB];
    __shared__ unsigned idxBuf[APB];

    const int t   = threadIdx.x;
    const int blk = blockIdx.x;

    gBase[t] = bucketBase[t] + hist[(size_t)t * NBLK + blk];
    lcnt[t] = 0u;
    __syncthreads();

    // pass 1: load pack words (kept in regs), count per-bucket
    const int blockBase = blk * APB;
    uint4 pw[4];
    #pragma unroll
    for (int g = 0; g < 4; ++g) {
        const int a0 = blockBase + (g * 256 + t) * 4;
        if (a0 < NATOMS) {
            pw[g] = *(const uint4*)(pack + a0);
            const unsigned* p = (const unsigned*)&pw[g];
            #pragma unroll
            for (int k = 0; k < 4; ++k)
                if (p[k] >> 20) atomicAdd(&lcnt[(p[k] >> 6) & 255u], 1u);
        } else {
            pw[g] = make_uint4(0u, 0u, 0u, 0u);
        }
    }
    __syncthreads();

    // local exclusive scan of lcnt -> lofs
    const unsigned lown = lcnt[t];
    sc[t] = lown;
    __syncthreads();
    for (int off = 1; off < 256; off <<= 1) {
        unsigned x = (t >= off) ? sc[t - off] : 0u;
        __syncthreads();
        sc[t] += x;
        __syncthreads();
    }
    lofs[t] = sc[t] - lown;
    lcnt[t] = 0u;
    __syncthreads();
    const unsigned total = sc[255];

    // pass 2: place survivors bucket-grouped in LDS
    #pragma unroll
    for (int g = 0; g < 4; ++g) {
        const int a0 = blockBase + (g * 256 + t) * 4;
        const unsigned* p = (const unsigned*)&pw[g];
        #pragma unroll
        for (int k = 0; k < 4; ++k) {
            const unsigned w = p[k];
            if (w >> 20) {
                const unsigned b    = (w >> 6) & 255u;
                const unsigned slot = atomicAdd(&lcnt[b], 1u);
                const unsigned pos  = lofs[b] + slot;
                wBuf[pos]   = w;
                idxBuf[pos] = (unsigned)(a0 + k);
            }
        }
    }
    __syncthreads();

    // write out: consecutive j -> same bucket run -> consecutive dest
    for (unsigned j = (unsigned)t; j < total; j += 256u) {
        const unsigned w = wBuf[j];
        const unsigned b = (w >> 6) & 255u;
        const unsigned dest = gBase[b] + (j - lofs[b]);
        sorted[dest] = make_uint2(w, idxBuf[j]);
    }
}

// ---------------------------------------------------------------------------
// Phase 4: accumulate. block = (bucket b, sub). LDS: 64 res x 6 planes.
// ---------------------------------------------------------------------------
__global__ __launch_bounds__(256)
void k_accum(const uint2* __restrict__ sorted,
             const float* __restrict__ contRat,
             const unsigned* __restrict__ bucketBase,
             float* __restrict__ accPart,          // [NBUCK][ACC_SUB][6][64]
             unsigned* __restrict__ resPart) {     // [NBUCK][ACC_SUB][64]
    __shared__ float acc[6 * 64];
    __shared__ unsigned ror[64];
    const int b   = blockIdx.x >> 3;
    const int sub = blockIdx.x & 7;

    for (int j = threadIdx.x; j < 384; j += 256) acc[j] = 0.0f;
    if (threadIdx.x < 64) ror[threadIdx.x] = 0u;
    __syncthreads();

    const unsigned s0 = bucketBase[b], s1 = bucketBase[b + 1];
    const unsigned len = s1 - s0;
    const unsigned lo = s0 + (unsigned)(((unsigned long long)len * sub) >> 3);
    const unsigned hi = s0 + (unsigned)(((unsigned long long)len * (sub + 1)) >> 3);

    for (unsigned i = lo + threadIdx.x; i < hi; i += 256u) {
        const uint2 e = sorted[i];
        const unsigned w = e.x;
        const int lr = (int)(w & 63u);
        const unsigned am = PK_AM(w);
        const float* cr = contRat + (size_t)e.y * 3;
        const int pb = PK_BB(w) ? 0 : 3;
        if (PK_BB(w)) atomicOr(&ror[lr], (am << 5) | PK_RES(w));
        if (am & 1) atomicAdd(&acc[(pb + 0) * 64 + lr], cr[0]);
        if (am & 2) atomicAdd(&acc[(pb + 1) * 64 + lr], cr[1]);
        if (am & 4) atomicAdd(&acc[(pb + 2) * 64 + lr], cr[2]);
    }
    __syncthreads();

    float* ap = accPart + ((size_t)b * ACC_SUB + sub) * 384;
    for (int j = threadIdx.x; j < 384; j += 256) ap[j] = acc[j];
    if (threadIdx.x < 64)
        resPart[((size_t)b * ACC_SUB + sub) * 64 + threadIdx.x] = ror[threadIdx.x];
}

// ---------------------------------------------------------------------------
// Phase 5: finalize. block b, thread t = lr*3+alt -> out[b*192+t] contiguous.
// ---------------------------------------------------------------------------
__global__ __launch_bounds__(192)
void k_finalize(const float* __restrict__ accPart,
                const unsigned* __restrict__ resPart,
                float* __restrict__ out,
                const float* __restrict__ mcmax,
                const float* __restrict__ mcmin,
                const float* __restrict__ scmax,
                const float* __restrict__ scmin) {
    const int b = blockIdx.x;
    const int t = threadIdx.x;            // 0..191
    const int lr = t / 3, alt = t - lr * 3;

    float m = 0.0f, v = 0.0f;
    unsigned rb = 0u;
    #pragma unroll
    for (int s = 0; s < ACC_SUB; ++s) {
        const float* ap = accPart + ((size_t)b * ACC_SUB + s) * 384;
        m  += ap[alt * 64 + lr];
        v  += ap[(3 + alt) * 64 + lr];
        rb |= resPart[((size_t)b * ACC_SUB + s) * 64 + lr];
    }

    if ((rb >> (5 + alt)) & 1u) {
        int resn = (int)(rb & 31u);
        if (resn > NRES - 1) resn = NRES - 1;
        m = (m - mcmin[resn]) / (mcmax[resn] - mcmin[resn]);
        v = ((rb & 31u) == GLY) ? 0.0f
                                : (v - scmin[resn]) / (scmax[resn] - scmin[resn]);
    }
    out[b * 192 + t]         = fminf(fmaxf(m, 0.0f), 1.0f);
    out[NBINS + b * 192 + t] = fminf(fmaxf(v, 0.0f), 1.0f);
}

// ---------------------------------------------------------------------------
// Fallback (tiny ws): flat agent-scope atomics (proven R1).
// ---------------------------------------------------------------------------
__global__ void k_init_flat(float* __restrict__ out, int* __restrict__ seq,
                            int* __restrict__ flag,
                            const unsigned char* __restrict__ altBytes) {
    int i = blockIdx.x * blockDim.x + threadIdx.x;
    if (i < NBINS) { out[i] = 0.0f; out[NBINS + i] = 0.0f; seq[i] = PADV; }
    if (blockIdx.x == 0 && threadIdx.x < 64) {
        unsigned char b = altBytes[threadIdx.x * 4 + 1];
        unsigned long long m = __ballot(b != 0);
        if (threadIdx.x == 0) *flag = (m != 0ULL) ? 1 : 0;
    }
}

__global__ void k_scatter_flat(const float* __restrict__ contRat,
                               const int* __restrict__ desc,
                               const unsigned char* __restrict__ altB,
                               const int* __restrict__ altI,
                               const int* __restrict__ flag,
                               float* __restrict__ mcArr,
                               float* __restrict__ scArr,
                               int* __restrict__ seq) {
    int a = blockIdx.x * blockDim.x + threadIdx.x;
    if (a >= NATOMS) return;
    const int atname  = desc[a * 5 + 0];
    const int resnum  = desc[a * 5 + 1];
    const int chain   = desc[a * 5 + 2];
    const int batchI  = desc[a * 5 + 3];
    const int resname = desc[a * 5 + 4];
    const bool valid = (atname != PADV);
    const bool is_bb = (atname >= 0) && (atname <= 3);
    const int  base  = ((batchI * NCHAIN + chain) * SEQL + resnum) * NALT;
    const bool byteLayout = (*flag != 0);
    #pragma unroll
    for (int alt = 0; alt < NALT; ++alt) {
        bool altv;
        if (byteLayout) altv = (altB[a * NALT + alt] != 0);
        else            altv = (altI[a * NALT + alt] != 0);
        if (altv && valid) {
            const float c = contRat[a * NALT + alt];
            const int   f = base + alt;
            if (is_bb) { atomicAdd(&mcArr[f], c); seq[f] = resname; }
            else       { atomicAdd(&scArr[f], c); }
        }
    }
}

__global__ void k_final_flat(float* __restrict__ mc, float* __restrict__ sc2,
                             const int* __restrict__ seq,
                             const float* __restrict__ mcmax,
                             const float* __restrict__ mcmin,
                             const float* __restrict__ scmax,
                             const float* __restrict__ scmin) {
    int i = blockIdx.x * blockDim.x + threadIdx.x;
    if (i >= NBINS) return;
    const int s = seq[i];
    float m = mc[i], v = sc2[i];
    if (s != PADV) {
        int idx = s < 0 ? 0 : (s > NRES - 1 ? NRES - 1 : s);
        m = (m - mcmin[idx]) / (mcmax[idx] - mcmin[idx]);
        if (s != GLY) v = (v - scmin[idx]) / (scmax[idx] - scmin[idx]);
        else          v = 0.0f;
    }
    mc[i]  = fminf(fmaxf(m, 0.0f), 1.0f);
    sc2[i] = fminf(fmaxf(v, 0.0f), 1.0f);
}

// ---------------------------------------------------------------------------
extern "C" void kernel_launch(void* const* d_in, const int* in_sizes, int n_in,
                              void* d_out, int out_size, void* d_ws, size_t ws_size,
                              hipStream_t stream) {
    const float* contRat = (const float*)d_in[0];
    const float* mcmax   = (const float*)d_in[1];
    const float* mcmin   = (const float*)d_in[2];
    const float* scmax   = (const float*)d_in[3];
    const float* scmin   = (const float*)d_in[4];
    const int*   desc    = (const int*)d_in[5];
    const void*  alts    = d_in[6];

    float* out = (float*)d_out;

    if (ws_size >= WS_NEED) {
        unsigned* pack  = (unsigned*)((char*)d_ws + OFF_PACK);
        unsigned* hist  = (unsigned*)((char*)d_ws + OFF_HIST);
        unsigned* tot   = (unsigned*)((char*)d_ws + OFF_TOT);
        unsigned* bbase = (unsigned*)((char*)d_ws + OFF_BB);
        uint2*    sorted= (uint2*)   ((char*)d_ws + OFF_SORT);
        float*    accP  = (float*)   ((char*)d_ws + OFF_ACC);
        unsigned* resP  = (unsigned*)((char*)d_ws + OFF_RES);

        k_pack_hist<<<NBLK, 256, 0, stream>>>(
            desc, (const unsigned char*)alts, (const int*)alts, pack, hist);
        k_prefix1<<<NBUCK, 256, 0, stream>>>(hist, tot);
        k_prefix2<<<1, 256, 0, stream>>>(tot, bbase);
        k_scatter<<<NBLK, 256, 0, stream>>>(pack, hist, bbase, sorted);
        k_accum<<<NBUCK * ACC_SUB, 256, 0, stream>>>(
            sorted, contRat, bbase, accP, resP);
        k_finalize<<<NBUCK, 192, 0, stream>>>(
            accP, resP, out, mcmax, mcmin, scmax, scmin);
    } else {
        // ws too small: flat agent-scope atomic path
        int* seq  = (int*)d_ws;
        int* flag = seq + NBINS;
        const int binBlocks = (NBINS + 255) / 256;
        k_init_flat<<<binBlocks, 256, 0, stream>>>(out, seq, flag,
                                                   (const unsigned char*)alts);
        k_scatter_flat<<<(NATOMS + 255) / 256, 256, 0, stream>>>(
            contRat, desc,
            (const unsigned char*)alts, (const int*)alts, flag,
            out, out + NBINS, seq);
        k_final_flat<<<binBlocks, 256, 0, stream>>>(
            out, out + NBINS, seq, mcmax, mcmin, scmax, scmin);
    }
}